// Round 12
// baseline (57.382 us; speedup 1.0000x reference)
//
#include <hip/hip_runtime.h>
#include <hip/hip_bf16.h>

// TreeCnnLayer: y[b,l,o] = relu( sum_{k=0..3} x[b, idx[l,k], :] . mask[k,:,o] + bias[127] )
// == GEMM: A[131072 x 512] (gathered, fp32->bf16) * Bm[512 x 128] (mask), fp32 out.
//
// R9 = R7 (46us) with the fp32-A root cause removed via a one-shot x->bf16 prepass:
//  - cvt_x: x fp32 -> g_xbf bf16 (33.5MB, L3-resident afterwards). 96MB HBM ~15us.
//  - main: 1 gll = 1 full bf16 A-row (512B x ... 16B/lane). Phase = 32 rows (pair of
//    16-row tiles): LDS 32KB, ring-2 = 64KB. Per kk: 2 ds_read_b128 + 2 B-loads +
//    4 MFMA -> B-L2 traffic halved vs R7, LDS bytes halved, zero cvt in loop.
//  - provably-safe counted vmcnt: in-order retirement (m135) => vmcnt(8) with >=8
//    ops issued after the target gll batch guarantees it landed.
//  - no register staging anywhere (R1/R3/R5/R8 all lost to the allocator).

namespace {

constexpr int kNodes = 8192;        // n+1 (row 8191 = sentinel; tab pad row -> idx 0)
constexpr int kIn = 128;
constexpr int kOut = 128;
constexpr int kThreads = 256;
constexpr int kGrid = 512;
constexpr int kPhases = 8;          // 32 rows/phase -> 256 rows/block

typedef __attribute__((ext_vector_type(8))) short short8;   // 8 bf16 (MFMA A/B frag)
typedef __attribute__((ext_vector_type(4))) float f32x4;

__device__ short8 g_bfrag[16 * 8 * 64];                     // 128 KiB B frags
__device__ __align__(16) short g_xbf[16 * kNodes * kIn];    // 33.5 MB bf16 x

__device__ __forceinline__ short f2bf(float f) {
  return __builtin_bit_cast(short, __float2bfloat16(f));    // RNE
}

template <int N>
__device__ __forceinline__ void waitvm() {
  asm volatile("s_waitcnt vmcnt(%0)" ::"n"(N) : "memory");
  __builtin_amdgcn_sched_barrier(0);
}
__device__ __forceinline__ void barrier() {
  __builtin_amdgcn_s_barrier();
  __builtin_amdgcn_sched_barrier(0);
}

// Prep: mask (4,128,128) fp32 -> bf16 MFMA-frag layout (verified R2-R8).
__global__ void prep_bfrag(const float* __restrict__ mask) {
  const int t = blockIdx.x * blockDim.x + threadIdx.x;
  const int kk = t >> 9, g = (t >> 6) & 7, lane = t & 63;
  const int krow = kk * 32 + (lane >> 4) * 8;
  const int col = g * 16 + (lane & 15);
  short8 pk;
#pragma unroll
  for (int e = 0; e < 8; ++e) pk[e] = f2bf(mask[(krow + e) * kOut + col]);
  g_bfrag[t] = pk;
}

// Prepass: x fp32 -> bf16, 8 elems/thread, grid 8192 x 256.
__global__ __launch_bounds__(256)
void cvt_x(const float* __restrict__ x) {
  const size_t t = (size_t)blockIdx.x * 256 + threadIdx.x;
  const f32x4 a = reinterpret_cast<const f32x4*>(x)[2 * t];
  const f32x4 b = reinterpret_cast<const f32x4*>(x)[2 * t + 1];
  short8 pk;
  pk[0] = f2bf(a[0]); pk[1] = f2bf(a[1]); pk[2] = f2bf(a[2]); pk[3] = f2bf(a[3]);
  pk[4] = f2bf(b[0]); pk[5] = f2bf(b[1]); pk[6] = f2bf(b[2]); pk[7] = f2bf(b[3]);
  reinterpret_cast<short8*>(g_xbf)[t] = pk;
}

__global__ __launch_bounds__(kThreads, 2)
void tree_gemm(const float* __restrict__ bias, float* __restrict__ y) {
  // ring-2 x 32 rows x 512 bf16 (1KB/row = 64 x 16B slots) = 64 KiB
  __shared__ __align__(16) short ldsA[2][32 * 512];

  const int tid  = threadIdx.x;
  const int lane = tid & 63;
  const int wv   = tid >> 6;   // wave 0..3
  const int l15  = lane & 15;
  const int l4   = lane >> 4;  // 0..3
  const int nbh  = lane >> 4;  // stage: neighbor this lane sources (XOR keeps hi bits)

  const float blast = bias[kOut - 1];

  // XCD-chunked bijective swizzle (512 % 8 == 0)
  const int sb = (blockIdx.x & 7) * (kGrid / 8) + (blockIdx.x >> 3);
  const int bb = sb >> 5;                    // batch 0..15
  const int blockRow0 = (sb & 31) * 256;     // node base (256 rows/block)
  const short* xbf = g_xbf + (size_t)bb * kNodes * kIn;

  // Stage phase p (32 bf16 A-rows) into ldsA[bufsel]; 1 gll = 1 row; wave wv does
  // rows rho = wv*8+j. Lane L: content slot c = L ^ (rho&7) (low-3-bit XOR, keeps
  // neighbor = L>>4); src = xbf[gi]*128 elems + ((L&15)^(rho&7))*8 shorts.
  auto stage = [&](int p, int bufsel) {
    const int r0 = blockRow0 + p * 32;
#pragma unroll
    for (int j = 0; j < 8; ++j) {
      const int rho = wv * 8 + j;
      const int v = r0 + rho;                          // wave-uniform node id
      const int par = (v > 0) ? ((v - 1) >> 1) : (kNodes - 1);
      const int f = 2 * v + 1;
      const int ch = (f < kNodes - 1) ? (f + (nbh & 1)) : (kNodes - 1);
      int gi = (nbh == 0) ? v : (nbh == 1) ? par : ch; // per-lane select
      if (v == kNodes - 1) gi = 0;                     // tab pad row is all-zero
      const short* src = xbf + (size_t)gi * kIn + (((lane & 15) ^ (rho & 7)) << 3);
      const short* dst = &ldsA[bufsel][rho * 512];     // uniform base; HW adds lane*16
      __builtin_amdgcn_global_load_lds(
          (const __attribute__((address_space(1))) void*)src,
          (__attribute__((address_space(3))) void*)dst, 16, 0, 0);
    }
  };

  const short8* gb = g_bfrag + wv * 2 * 64 + lane;  // wave's colgrps {2wv, 2wv+1}

  auto compute = [&](int p) {
    const short* buf = ldsA[p & 1];
    f32x4 acc00 = {}, acc01 = {}, acc10 = {}, acc11 = {};
#pragma unroll
    for (int kk = 0; kk < 16; ++kk) {
      const short8 b0 = gb[kk * 512];        // L2-resident B stream
      const short8 b1 = gb[kk * 512 + 64];
      const int slot = (kk * 4 + l4) ^ (l15 & 7);   // (16+l15)&7 == l15&7: same slot
      const short8 a0 = *reinterpret_cast<const short8*>(buf + l15 * 512 + slot * 8);
      const short8 a1 = *reinterpret_cast<const short8*>(buf + (16 + l15) * 512 + slot * 8);
      acc00 = __builtin_amdgcn_mfma_f32_16x16x32_bf16(a0, b0, acc00, 0, 0, 0);
      acc01 = __builtin_amdgcn_mfma_f32_16x16x32_bf16(a0, b1, acc01, 0, 0, 0);
      acc10 = __builtin_amdgcn_mfma_f32_16x16x32_bf16(a1, b0, acc10, 0, 0, 0);
      acc11 = __builtin_amdgcn_mfma_f32_16x16x32_bf16(a1, b1, acc11, 0, 0, 0);
    }
    // D frag: col = lane&15, row = (lane>>4)*4 + r (m89-verified, matches R2-R8)
    const int r0 = blockRow0 + p * 32;
    float* yb = y + ((size_t)bb * kNodes + r0) * kOut;
    const int oc = wv * 32 + l15;
#pragma unroll
    for (int r = 0; r < 4; ++r) {
      const int row = l4 * 4 + r;
      const float v00 = acc00[r] + blast, v01 = acc01[r] + blast;
      const float v10 = acc10[r] + blast, v11 = acc11[r] + blast;
      yb[row * kOut + oc]             = v00 > 0.f ? v00 : 0.f;
      yb[row * kOut + oc + 16]        = v01 > 0.f ? v01 : 0.f;
      yb[(16 + row) * kOut + oc]      = v10 > 0.f ? v10 : 0.f;
      yb[(16 + row) * kOut + oc + 16] = v11 > 0.f ? v11 : 0.f;
    }
  };

  // ---- ring-2 pipeline, counted vmcnt (safe via in-order suffix invariant) ----
  stage(0, 0);
  stage(1, 1);
  for (int p = 0; p < kPhases; ++p) {
    // >=8 vmem ops were issued after gll_p's batch (gll_{p+1} at p=0; B/stores+gll
    // later) -> vmcnt(8) proves gll_p retired. Never drains the newest prefetch.
    waitvm<8>();
    barrier();
    compute(p);
    barrier();                       // all waves done reading buf[p&1]
    if (p + 2 < kPhases) stage(p + 2, p & 1);
  }
}

}  // namespace

extern "C" void kernel_launch(void* const* d_in, const int* in_sizes, int n_in,
                              void* d_out, int out_size, void* d_ws, size_t ws_size,
                              hipStream_t stream) {
  const float* x    = (const float*)d_in[0];
  const float* mask = (const float*)d_in[1];
  const float* bias = (const float*)d_in[2];
  float*       y    = (float*)d_out;
  (void)in_sizes; (void)n_in; (void)out_size; (void)d_ws; (void)ws_size;

  prep_bfrag<<<dim3(32), dim3(256), 0, stream>>>(mask);
  cvt_x<<<dim3(8192), dim3(256), 0, stream>>>(x);
  tree_gemm<<<dim3(kGrid), dim3(kThreads), 0, stream>>>(bias, y);
}

// Round 13
// 51.387 us; speedup vs baseline: 1.1167x; 1.1167x over previous
//
#include <hip/hip_runtime.h>
#include <hip/hip_bf16.h>

// TreeCnnLayer: y[b,l,o] = relu( sum_{k=0..3} x[b, idx[l,k], :] . mask[k,:,o] + bias[127] )
// == GEMM: A[131072 x 512] (gathered, fp32->bf16) * Bm[512 x 128] (mask), fp32 out.
//
// R13: back to R7's no-prepass fp32 staging (R9's cvt_x prepass cost a serialized
// ~20us memory-floor kernel -> net loss). R7 was L2-BW/latency co-bound:
//   - B streamed 1KB per MFMA (1 GB L2)  -> fix: 2 row-tiles per wave, B reuse x2
//   - 64KB LDS -> 8 waves/CU             -> fix: phase = 32 rows x K-quarter(128)
//     = 16KB fp32, ring-2 = 32KB -> 4 blocks/CU = 16 waves/CU
//   - K-quarter == one neighbor class (self/parent/ch0/ch1): gather = 1 x-row per
//     32-lane half-gll; acc carries across the 4 K-phases of a rowgroup.
// Kept: global_load_lds (no reg staging arrays - R1/R3/R5/R8 all spilled),
// arithmetic heap indices, counted vmcnt(4) (suffix-safe w/ in-order retirement),
// verified swizzle + frag layout + epilogue, XCD-chunked block swizzle.

namespace {

constexpr int kNodes = 8192;        // n+1 (row 8191 = sentinel; tab pad row -> idx 0)
constexpr int kIn = 128;
constexpr int kOut = 128;
constexpr int kThreads = 256;
constexpr int kGrid = 1024;         // 128 GEMM-rows per block
constexpr int kPhases = 16;         // 4 rowgroups(32 rows) x 4 K-quarters

typedef __attribute__((ext_vector_type(8))) short short8;   // 8 bf16 (MFMA A/B frag)
typedef __attribute__((ext_vector_type(4))) float f32x4;

__device__ short8 g_bfrag[16 * 8 * 64];                     // 128 KiB B frags (L2-hot)

__device__ __forceinline__ short f2bf(float f) {
  return __builtin_bit_cast(short, __float2bfloat16(f));    // RNE
}

template <int N>
__device__ __forceinline__ void waitvm() {
  asm volatile("s_waitcnt vmcnt(%0)" ::"n"(N) : "memory");
  __builtin_amdgcn_sched_barrier(0);
}
__device__ __forceinline__ void barrier() {
  __builtin_amdgcn_s_barrier();
  __builtin_amdgcn_sched_barrier(0);
}

// Prep: mask (4,128,128) fp32 -> bf16 MFMA-frag layout (verified R2-R12).
__global__ void prep_bfrag(const float* __restrict__ mask) {
  const int t = blockIdx.x * blockDim.x + threadIdx.x;
  const int kk = t >> 9, g = (t >> 6) & 7, lane = t & 63;
  const int krow = kk * 32 + (lane >> 4) * 8;
  const int col = g * 16 + (lane & 15);
  short8 pk;
#pragma unroll
  for (int e = 0; e < 8; ++e) pk[e] = f2bf(mask[(krow + e) * kOut + col]);
  g_bfrag[t] = pk;
}

__global__ __launch_bounds__(kThreads, 4)
void tree_gemm(const float* __restrict__ x, const float* __restrict__ bias,
               float* __restrict__ y) {
  // ring-2 x (32 rows x 128 floats = one neighbor-class K-quarter) = 32 KiB
  __shared__ __align__(16) float ldsA[2][32 * kIn];

  const int tid  = threadIdx.x;
  const int lane = tid & 63;
  const int wv   = tid >> 6;   // wave 0..3 -> colgrps {2wv, 2wv+1}
  const int l15  = lane & 15;
  const int l4   = lane >> 4;  // 0..3
  const int lh   = lane >> 5;  // 0..1: which row of the gll's row-pair
  const int l31  = lane & 31;

  const float blast = bias[kOut - 1];

  // XCD-chunked bijective swizzle (1024 % 8 == 0)
  const int sb = (blockIdx.x & 7) * (kGrid / 8) + (blockIdx.x >> 3);
  const int bb = sb >> 6;                    // batch 0..15 (64 blocks/batch)
  const int blockRow0 = (sb & 63) * 128;     // node base (128 rows/block)
  const float* xb = x + (size_t)bb * kNodes * kIn;

  // Stage phase p = (rowgroup rg, K-quarter kq): 32 x-rows (one neighbor class),
  // 16 gll x 1KB (gll i = rows {2i, 2i+1}; lanes 0-31 / 32-63). LDS dest linear;
  // source pre-swizzled by (row&7) in 16B slots (rule #21); read XORs it back.
  auto stage = [&](int p, int bufsel) {
    const int rg = p >> 2, kq = p & 3;
    const int r0 = blockRow0 + rg * 32;
#pragma unroll
    for (int j = 0; j < 4; ++j) {
      const int i   = wv * 4 + j;            // gll index 0..15
      const int row = 2 * i + lh;            // row within tile (per-lane)
      const int v   = r0 + row;              // node id
      int gi;
      if (kq == 0) {
        gi = v;                              // self
      } else if (kq == 1) {
        gi = (v > 0) ? ((v - 1) >> 1) : (kNodes - 1);   // parent
      } else {
        const int f = 2 * v + 1;             // children (clamped to sentinel)
        gi = (f < kNodes - 1) ? (f + (kq - 2)) : (kNodes - 1);
      }
      if (v == kNodes - 1) gi = 0;           // tab pad row is all-zero
      const float* src = xb + (size_t)gi * kIn + ((l31 ^ (row & 7)) << 2);
      float* dst = &ldsA[bufsel][i * 256];   // uniform base; HW adds lane*16B
      __builtin_amdgcn_global_load_lds(
          (const __attribute__((address_space(1))) void*)src,
          (__attribute__((address_space(3))) void*)dst, 16, 0, 0);
    }
  };

  const short8* gb = g_bfrag + wv * 2 * 64 + lane;  // wave's colgrps {2wv, 2wv+1}

  const f32x4 vzero = {};
  f32x4 a00 = {}, a01 = {}, a10 = {}, a11 = {};     // [rowtile][colgrp]

  stage(0, 0);
  stage(1, 1);

  for (int p = 0; p < kPhases; ++p) {
    // suffix-safe: >=8 B-loads (+16 stores on kq3) + 4 gll issued after gll(p)'s
    // batch; in-order retirement (m135) => outstanding<=4 proves gll(p) landed.
    waitvm<4>();
    barrier();

    const float* buf = ldsA[p & 1];
    const int kq = p & 3;
    if (kq == 0) { a00 = vzero; a01 = vzero; a10 = vzero; a11 = vzero; }

#pragma unroll
    for (int kk = 0; kk < 4; ++kk) {
      const int kkg = kq * 4 + kk;           // global K-step 0..15
      const short8 b0 = gb[kkg * 512];       // L2-hot B stream, reused x2 rowtiles
      const short8 b1 = gb[kkg * 512 + 64];
      const int q  = kk * 8 + l4 * 2;        // content slot (16B units)
      const int s0 = q ^ (l15 & 7);          // swizzled slots; (16+l15)&7 == l15&7
      const int s1 = (q + 1) ^ (l15 & 7);
      const float* r0p = buf + l15 * kIn;
      const float* r1p = buf + (16 + l15) * kIn;
      const f32x4 lo0 = *reinterpret_cast<const f32x4*>(r0p + s0 * 4);
      const f32x4 hi0 = *reinterpret_cast<const f32x4*>(r0p + s1 * 4);
      const f32x4 lo1 = *reinterpret_cast<const f32x4*>(r1p + s0 * 4);
      const f32x4 hi1 = *reinterpret_cast<const f32x4*>(r1p + s1 * 4);
      short8 fa0, fa1;
      fa0[0] = f2bf(lo0[0]); fa0[1] = f2bf(lo0[1]); fa0[2] = f2bf(lo0[2]); fa0[3] = f2bf(lo0[3]);
      fa0[4] = f2bf(hi0[0]); fa0[5] = f2bf(hi0[1]); fa0[6] = f2bf(hi0[2]); fa0[7] = f2bf(hi0[3]);
      fa1[0] = f2bf(lo1[0]); fa1[1] = f2bf(lo1[1]); fa1[2] = f2bf(lo1[2]); fa1[3] = f2bf(lo1[3]);
      fa1[4] = f2bf(hi1[0]); fa1[5] = f2bf(hi1[1]); fa1[6] = f2bf(hi1[2]); fa1[7] = f2bf(hi1[3]);
      a00 = __builtin_amdgcn_mfma_f32_16x16x32_bf16(fa0, b0, a00, 0, 0, 0);
      a01 = __builtin_amdgcn_mfma_f32_16x16x32_bf16(fa0, b1, a01, 0, 0, 0);
      a10 = __builtin_amdgcn_mfma_f32_16x16x32_bf16(fa1, b0, a10, 0, 0, 0);
      a11 = __builtin_amdgcn_mfma_f32_16x16x32_bf16(fa1, b1, a11, 0, 0, 0);
    }

    if (kq == 3) {
      // D frag: col = lane&15, row = (lane>>4)*4 + r (m89-verified, R2-R12)
      const int r0 = blockRow0 + (p >> 2) * 32;
      float* yb = y + ((size_t)bb * kNodes + r0) * kOut;
      const int oc = wv * 32 + l15;
#pragma unroll
      for (int r = 0; r < 4; ++r) {
        const int row = l4 * 4 + r;
        const float v00 = a00[r] + blast, v01 = a01[r] + blast;
        const float v10 = a10[r] + blast, v11 = a11[r] + blast;
        yb[row * kOut + oc]             = v00 > 0.f ? v00 : 0.f;
        yb[row * kOut + oc + 16]        = v01 > 0.f ? v01 : 0.f;
        yb[(16 + row) * kOut + oc]      = v10 > 0.f ? v10 : 0.f;
        yb[(16 + row) * kOut + oc + 16] = v11 > 0.f ? v11 : 0.f;
      }
    }

    barrier();                       // all waves done reading buf[p&1]
    if (p + 2 < kPhases) stage(p + 2, p & 1);
  }
}

}  // namespace

extern "C" void kernel_launch(void* const* d_in, const int* in_sizes, int n_in,
                              void* d_out, int out_size, void* d_ws, size_t ws_size,
                              hipStream_t stream) {
  const float* x    = (const float*)d_in[0];
  const float* mask = (const float*)d_in[1];
  const float* bias = (const float*)d_in[2];
  float*       y    = (float*)d_out;
  (void)in_sizes; (void)n_in; (void)out_size; (void)d_ws; (void)ws_size;

  prep_bfrag<<<dim3(32), dim3(256), 0, stream>>>(mask);
  tree_gemm<<<dim3(kGrid), dim3(kThreads), 0, stream>>>(x, bias, y);
}